// Round 7
// baseline (419.061 us; speedup 1.0000x reference)
//
#include <hip/hip_runtime.h>

#define CI 32
#define CO 32

constexpr float INV_S = 1.0f / 256.0f;
constexpr float THETA = 6.28318530717958647692f / 256.0f;

// cos/sin(2*pi*k/256), k=0..15 — compile-time rotation constants.
__device__ constexpr float RC[16] = {
  1.0f,          0.9996988187f, 0.9987954562f, 0.9972904567f,
  0.9951847267f, 0.9924795346f, 0.9891765100f, 0.9852776424f,
  0.9807852804f, 0.9757021300f, 0.9700312532f, 0.9637760658f,
  0.9569403357f, 0.9495281806f, 0.9415440652f, 0.9329927988f};
__device__ constexpr float RS[16] = {
  0.0f,          0.0245412285f, 0.0490676743f, 0.0735645636f,
  0.0980171403f, 0.1224106752f, 0.1467304745f, 0.1709618888f,
  0.1950903220f, 0.2191012402f, 0.2429801799f, 0.2667127575f,
  0.2902846773f, 0.3136817404f, 0.3368898534f, 0.3598950365f};

// -------------------------------------------------------------------------
// K1: truncated forward DHT. TWO blocks per (b,i) image (split over rows to
// double occupancy: 1024 blocks = 4 blocks/CU, 16 waves/CU). Lane = column.
//   half 0: rows 0,128 + pairs n=1..63   (twiddle init n=1: RC/RS consts)
//   half 1: pairs n=64..127              (twiddle init n=64: exact pi/2*k)
// Each half runs stage 2 on its partial C1/S1 and writes a partial xh;
// k_mid sums the two partials. No sincosf in stage 1 at all.
// -------------------------------------------------------------------------
__global__ __launch_bounds__(256, 4) void k_fwd(const float* __restrict__ x,
                                                float* __restrict__ xh) {
  __shared__ __align__(16) float C1[16][260];  // pad: k1-rows on distinct banks
  __shared__ __align__(16) float S1[16][260];
  const int t = threadIdx.x;
  const int img = blockIdx.x >> 1;
  const int half = blockIdx.x & 1;
  const float* __restrict__ xp = x + (size_t)img * 65536 + t;

  float aC[16], aS[16], tc[16], ts[16];

  auto doPair = [&](float lo, float hi) {
    float es = lo + hi, ds = lo - hi;
    #pragma unroll
    for (int k = 0; k < 16; ++k) {
      aC[k] = fmaf(es, tc[k], aC[k]);
      aS[k] = fmaf(ds, ts[k], aS[k]);
      float nc = fmaf(-ts[k], RS[k], tc[k] * RC[k]);  // rotate by THETA*k
      float ns = fmaf(tc[k], RS[k], ts[k] * RC[k]);
      tc[k] = nc; ts[k] = ns;
    }
  };

  const int m0 = half ? 72 : 8;  // first pair of the 7x8 main loop
  float xl[8], xr[8], nl[8], nr[8];

  // prologue loads
  if (half == 0) {
    #pragma unroll
    for (int j = 0; j < 7; ++j) {        // pairs 1..7
      xl[j] = xp[(1 + j) * 256];
      xr[j] = xp[(255 - j) * 256];
    }
  } else {
    #pragma unroll
    for (int j = 0; j < 8; ++j) {        // pairs 64..71
      xl[j] = xp[(64 + j) * 256];
      xr[j] = xp[(192 - j) * 256];       // 256-(64+j)
    }
  }
  // chunk-0 main loads in flight
  #pragma unroll
  for (int j = 0; j < 8; ++j) {
    nl[j] = xp[(m0 + j) * 256];
    nr[j] = xp[(256 - m0 - j) * 256];
  }

  // twiddle + accumulator init, then compute prologue
  if (half == 0) {
    #pragma unroll
    for (int k = 0; k < 16; ++k) { tc[k] = RC[k]; ts[k] = RS[k]; }
    float x0 = xp[0];
    float xm = xp[128 * 256];
    float e = x0 + xm, o = x0 - xm;      // rows 0,128: sin=0; cos=1,(-1)^k
    #pragma unroll
    for (int k = 0; k < 16; ++k) { aC[k] = (k & 1) ? o : e; aS[k] = 0.f; }
    #pragma unroll
    for (int j = 0; j < 7; ++j) doPair(xl[j], xr[j]);
  } else {
    #pragma unroll
    for (int k = 0; k < 16; ++k) {       // angle = (pi/2)*k, exact
      const int m = k & 3;
      tc[k] = (m == 0) ? 1.f : (m == 2) ? -1.f : 0.f;
      ts[k] = (m == 1) ? 1.f : (m == 3) ? -1.f : 0.f;
      aC[k] = 0.f; aS[k] = 0.f;
    }
    #pragma unroll
    for (int j = 0; j < 8; ++j) doPair(xl[j], xr[j]);
  }
  #pragma unroll
  for (int j = 0; j < 8; ++j) { xl[j] = nl[j]; xr[j] = nr[j]; }

  // main: 7 chunks of 8 pairs (m0 .. m0+55)
  for (int c = 0; c < 7; ++c) {
    if (c < 6) {
      const int nx = m0 + 8 * (c + 1);
      #pragma unroll
      for (int j = 0; j < 8; ++j) {
        nl[j] = xp[(nx + j) * 256];
        nr[j] = xp[(256 - nx - j) * 256];
      }
    }
    #pragma unroll
    for (int j = 0; j < 8; ++j) doPair(xl[j], xr[j]);
    #pragma unroll
    for (int j = 0; j < 8; ++j) { xl[j] = nl[j]; xr[j] = nr[j]; }
  }

  #pragma unroll
  for (int k = 0; k < 16; ++k) { C1[k][t] = aC[k]; S1[k][t] = aS[k]; }
  __syncthreads();

  // stage 2: partial Xh[k1,k2] = (1/256) sum_n2 [ C1*(c+s) + S1*(c-s) ],
  // (c,s) by per-lane recurrence, exact restart each 64 (quadrant).
  const int k1 = t >> 4, k2 = t & 15;
  float rc2, rs2;
  sincosf(THETA * (float)k2, &rs2, &rc2);
  float acc = 0.f;
  #pragma unroll
  for (int q = 0; q < 4; ++q) {
    const int m = (q * k2) & 3;  // state at n2=64q: angle = (pi/2)*q*k2
    float cc = (m == 0) ? 1.f : (m == 2) ? -1.f : 0.f;
    float ss = (m == 1) ? 1.f : (m == 3) ? -1.f : 0.f;
    #pragma unroll 2
    for (int n2 = q * 64; n2 < q * 64 + 64; n2 += 4) {
      float c4[4], s4[4];
      *(float4*)c4 = *(const float4*)&C1[k1][n2];
      *(float4*)s4 = *(const float4*)&S1[k1][n2];
      #pragma unroll
      for (int jj = 0; jj < 4; ++jj) {
        acc = fmaf(c4[jj], cc + ss, acc);
        acc = fmaf(s4[jj], cc - ss, acc);
        float nc = fmaf(-ss, rs2, cc * rc2);
        float ns = fmaf(cc, rs2, ss * rc2);
        cc = nc; ss = ns;
      }
    }
  }
  xh[(size_t)half * 131072 + (size_t)img * 256 + t] = acc * INV_S;
}

// -------------------------------------------------------------------------
// K2: mode mix + inverse-DHT stage A, one block per (b,o).
//   res = 0.5 * sum_i [ x*(w+wn) + xn*(w-wn) ],  n-index = (-k) mod 16
//   W[n1][j]    = sum_k1 res[k1][j]*cos(THETA*k1*n1)   (rows 0..128)
//   W[n1][16+j] = sum_k1 res[k1][j]*sin(THETA*k1*n1)
// Stage B: all 256 threads: (row = t&127, h = t>>7) does j = 8h..8h+7.
// -------------------------------------------------------------------------
__global__ __launch_bounds__(256, 2) void k_mid(const float* __restrict__ xh,
                                                const float* __restrict__ w,
                                                float* __restrict__ Wout) {
  __shared__ float xs[CI][256];
  __shared__ __align__(16) float rsm[256];
  const int t = threadIdx.x;
  const int b = blockIdx.x >> 5;
  const int o = blockIdx.x & 31;

  #pragma unroll 8
  for (int i = 0; i < CI; ++i) {
    const size_t p = (size_t)(b * CI + i) * 256 + t;
    xs[i][t] = xh[p] + xh[131072 + p];  // sum the two k_fwd partials
  }
  __syncthreads();

  const int k1 = t >> 4, k2 = t & 15;
  const int tn = (((16 - k1) & 15) << 4) | ((16 - k2) & 15);
  float acc = 0.f;
  #pragma unroll 8
  for (int i = 0; i < CI; ++i) {
    const float* __restrict__ wrow = w + (size_t)(i * CO + o) * 256;
    float wp = wrow[t];
    float wn = wrow[tn];  // gather within 1 KB row: L1/L2 hit
    acc = fmaf(xs[i][t], wp + wn, acc);
    acc = fmaf(xs[i][tn], wp - wn, acc);
  }
  rsm[t] = 0.5f * acc;
  __syncthreads();

  const int row = t & 127, h = t >> 7;
  float cc[16], ss[16];
  #pragma unroll
  for (int k = 0; k < 16; ++k)
    sincosf(THETA * (float)((k * row) & 255), &ss[k], &cc[k]);
  float U[8], V[8];
  #pragma unroll
  for (int j = 0; j < 8; ++j) { U[j] = 0.f; V[j] = 0.f; }
  #pragma unroll
  for (int k = 0; k < 16; ++k) {
    float ra[8];
    *(float4*)&ra[0] = *(const float4*)&rsm[k * 16 + 8 * h];
    *(float4*)&ra[4] = *(const float4*)&rsm[k * 16 + 8 * h + 4];
    #pragma unroll
    for (int j = 0; j < 8; ++j) {
      U[j] = fmaf(cc[k], ra[j], U[j]);
      V[j] = fmaf(ss[k], ra[j], V[j]);
    }
  }
  float* __restrict__ wr = Wout + (size_t)blockIdx.x * 4160 + row * 32 + 8 * h;
  {
    float4 u0 = {U[0]*INV_S, U[1]*INV_S, U[2]*INV_S, U[3]*INV_S};
    float4 u1 = {U[4]*INV_S, U[5]*INV_S, U[6]*INV_S, U[7]*INV_S};
    float4 v0 = {V[0]*INV_S, V[1]*INV_S, V[2]*INV_S, V[3]*INV_S};
    float4 v1 = {V[4]*INV_S, V[5]*INV_S, V[6]*INV_S, V[7]*INV_S};
    *(float4*)&wr[0] = u0; *(float4*)&wr[4] = u1;
    *(float4*)&wr[16] = v0; *(float4*)&wr[20] = v1;
  }

  if (row == 0) {  // row 128: cos(pi*k1) = (-1)^k1, sin = 0
    float U8[8];
    #pragma unroll
    for (int j = 0; j < 8; ++j) U8[j] = 0.f;
    #pragma unroll
    for (int k = 0; k < 16; ++k) {
      float ra[8];
      *(float4*)&ra[0] = *(const float4*)&rsm[k * 16 + 8 * h];
      *(float4*)&ra[4] = *(const float4*)&rsm[k * 16 + 8 * h + 4];
      #pragma unroll
      for (int j = 0; j < 8; ++j)
        U8[j] = (k & 1) ? (U8[j] - ra[j]) : (U8[j] + ra[j]);
    }
    float* __restrict__ wr8 = Wout + (size_t)blockIdx.x * 4160 + 128 * 32 + 8 * h;
    float4 a0 = {U8[0]*INV_S, U8[1]*INV_S, U8[2]*INV_S, U8[3]*INV_S};
    float4 a1 = {U8[4]*INV_S, U8[5]*INV_S, U8[6]*INV_S, U8[7]*INV_S};
    float4 z = {0.f, 0.f, 0.f, 0.f};
    *(float4*)&wr8[0] = a0; *(float4*)&wr8[4] = a1;
    *(float4*)&wr8[16] = z; *(float4*)&wr8[20] = z;
  }
}

// -------------------------------------------------------------------------
// K3: inverse-DHT stage B. 2 blocks per (b,o); lane = column n2.
// W rows via uniform VMEM float4 loads (L2-hit); per-lane twiddles in
// registers; row-pair symmetry gives 2 output rows per W row. Zero LDS.
// -------------------------------------------------------------------------
__global__ __launch_bounds__(256, 4) void k_invB(const float* __restrict__ Wb,
                                                 float* __restrict__ out) {
  const int t = threadIdx.x;
  const int img = blockIdx.x >> 1;
  const int half = blockIdx.x & 1;

  float cp[16], cm[16];
  #pragma unroll
  for (int k = 0; k < 16; ++k) {
    float s, c;
    sincosf(THETA * (float)((k * t) & 255), &s, &c);
    cp[k] = c + s;
    cm[k] = c - s;
  }

  const float* __restrict__ wbase = Wb + (size_t)img * 4160;
  float* __restrict__ op = out + (size_t)img * 65536 + t;

  const int n_lo = half ? 65 : 0;
  const int n_hi = half ? 128 : 64;
  #pragma unroll 2
  for (int n = n_lo; n <= n_hi; ++n) {
    float uu[16], vv[16];
    #pragma unroll
    for (int q = 0; q < 4; ++q) {
      *(float4*)&uu[4 * q] = *(const float4*)(wbase + n * 32 + 4 * q);
      *(float4*)&vv[4 * q] = *(const float4*)(wbase + n * 32 + 16 + 4 * q);
    }
    float a = 0.f, bsum = 0.f;
    #pragma unroll
    for (int k = 0; k < 16; ++k) {
      a = fmaf(uu[k], cp[k], a);
      bsum = fmaf(vv[k], cm[k], bsum);
    }
    op[(size_t)n * 256] = a + bsum;
    if (n >= 1 && n <= 127) op[(size_t)(256 - n) * 256] = a - bsum;
  }
}

extern "C" void kernel_launch(void* const* d_in, const int* in_sizes, int n_in,
                              void* d_out, int out_size, void* d_ws, size_t ws_size,
                              hipStream_t stream) {
  const float* x = (const float*)d_in[0];   // [16, 32, 256, 256] f32
  const float* w = (const float*)d_in[1];   // [32, 32, 16, 16]  f32
  float* out = (float*)d_out;               // [16, 32, 256, 256] f32

  float* xhb = (float*)d_ws;                // [2][512][256]  (1 MB, partials)
  float* Wb  = xhb + 262144;                // [512][130][32] (~8.5 MB)

  k_fwd<<<2 * 16 * CI, 256, 0, stream>>>(x, xhb);    // 1024 blocks
  k_mid<<<16 * CO, 256, 0, stream>>>(xhb, w, Wb);    // 512 blocks
  k_invB<<<2 * 16 * CO, 256, 0, stream>>>(Wb, out);  // 1024 blocks
}

// Round 9
// 272.692 us; speedup vs baseline: 1.5368x; 1.5368x over previous
//
#include <hip/hip_runtime.h>

#define CI 32
#define CO 32

constexpr float INV_S = 1.0f / 256.0f;
constexpr float THETA = 6.28318530717958647692f / 256.0f;
constexpr float RC1 = 0.99969881869620422266f;  // cos(2*pi/256)
constexpr float RS1 = 0.02454122852291228803f;  // sin(2*pi/256)

// -------------------------------------------------------------------------
// K1: truncated forward DHT. TWO blocks per (b,i) image (row-split), grid
// 1024. Lane = column n2. Per row-pair, twiddles for k=0..15 come from the
// Chebyshev recurrence c_k = 2c*c_{k-1} - c_{k-2} (1 FMA per trig value,
// state = single (c,s) pair -> ~30 fewer live VGPRs than tc/ts[16]).
//   half 0: rows 0,128 + pairs n=1..63   ((c,s) init at n=1, exact consts)
//   half 1: pairs n=64..127              ((c,s) init at n=64 = (0,1) exact)
// Each half runs stage 2 on its partial C1/S1, writes partial xh; k_mid sums.
// -------------------------------------------------------------------------
__global__ __launch_bounds__(256, 3) void k_fwd(const float* __restrict__ x,
                                                float* __restrict__ xh) {
  __shared__ __align__(16) float C1[16][260];  // pad: k1-rows on distinct banks
  __shared__ __align__(16) float S1[16][260];
  const int t = threadIdx.x;
  const int img = blockIdx.x >> 1;
  const int half = blockIdx.x & 1;
  const float* __restrict__ xp = x + (size_t)img * 65536 + t;

  float aC[16], aS[16];
  float c, s;  // twiddle (cos,sin)(THETA*n) at current pair n

  auto doPair = [&](float lo, float hi) {
    float es = lo + hi, ds = lo - hi;
    aC[0] += es;                       // k=0: cos=1, sin=0
    aC[1] = fmaf(es, c, aC[1]);        // k=1
    aS[1] = fmaf(ds, s, aS[1]);
    float tc2 = c + c;
    float ck2 = 1.f, ck1 = c, sk2 = 0.f, sk1 = s;
    #pragma unroll
    for (int k = 2; k < 16; ++k) {
      float ck = fmaf(tc2, ck1, -ck2);
      float sk = fmaf(tc2, sk1, -sk2);
      aC[k] = fmaf(es, ck, aC[k]);
      aS[k] = fmaf(ds, sk, aS[k]);
      ck2 = ck1; ck1 = ck;
      sk2 = sk1; sk1 = sk;
    }
    float nc = fmaf(c, RC1, -s * RS1);  // rotate (c,s) by THETA
    float ns = fmaf(c, RS1, s * RC1);
    c = nc; s = ns;
  };

  const int m0 = half ? 72 : 8;  // first pair of the 7x8 main loop
  float xl[8], xr[8], nl[8], nr[8];

  // prologue loads
  if (half == 0) {
    #pragma unroll
    for (int j = 0; j < 7; ++j) {        // pairs 1..7
      xl[j] = xp[(1 + j) * 256];
      xr[j] = xp[(255 - j) * 256];
    }
  } else {
    #pragma unroll
    for (int j = 0; j < 8; ++j) {        // pairs 64..71
      xl[j] = xp[(64 + j) * 256];
      xr[j] = xp[(192 - j) * 256];
    }
  }
  // chunk-0 main loads in flight
  #pragma unroll
  for (int j = 0; j < 8; ++j) {
    nl[j] = xp[(m0 + j) * 256];
    nr[j] = xp[(256 - m0 - j) * 256];
  }

  // init + compute prologue
  if (half == 0) {
    c = RC1; s = RS1;                    // n=1
    float x0 = xp[0];
    float xm = xp[128 * 256];
    float e = x0 + xm, o = x0 - xm;      // rows 0,128: sin=0; cos=1,(-1)^k
    #pragma unroll
    for (int k = 0; k < 16; ++k) { aC[k] = (k & 1) ? o : e; aS[k] = 0.f; }
    #pragma unroll
    for (int j = 0; j < 7; ++j) doPair(xl[j], xr[j]);
  } else {
    c = 0.f; s = 1.f;                    // n=64: angle pi/2, exact
    #pragma unroll
    for (int k = 0; k < 16; ++k) { aC[k] = 0.f; aS[k] = 0.f; }
    #pragma unroll
    for (int j = 0; j < 8; ++j) doPair(xl[j], xr[j]);
  }
  #pragma unroll
  for (int j = 0; j < 8; ++j) { xl[j] = nl[j]; xr[j] = nr[j]; }

  // main: 7 chunks of 8 pairs (m0 .. m0+55)
  for (int cch = 0; cch < 7; ++cch) {
    if (cch < 6) {
      const int nx = m0 + 8 * (cch + 1);
      #pragma unroll
      for (int j = 0; j < 8; ++j) {
        nl[j] = xp[(nx + j) * 256];
        nr[j] = xp[(256 - nx - j) * 256];
      }
    }
    #pragma unroll
    for (int j = 0; j < 8; ++j) doPair(xl[j], xr[j]);
    #pragma unroll
    for (int j = 0; j < 8; ++j) { xl[j] = nl[j]; xr[j] = nr[j]; }
  }

  #pragma unroll
  for (int k = 0; k < 16; ++k) { C1[k][t] = aC[k]; S1[k][t] = aS[k]; }
  __syncthreads();

  // stage 2: partial Xh[k1,k2] = (1/256) sum_n2 [ C1*(c+s) + S1*(c-s) ].
  // (cp,cm) = (cos+sin, cos-sin)(THETA*k2*n2) rotated directly:
  //   cp' = rc*cp + rs*cm ; cm' = rc*cm - rs*cp   (exact restart per 64)
  const int k1 = t >> 4, k2 = t & 15;
  float rc2, rs2;
  sincosf(THETA * (float)k2, &rs2, &rc2);
  float acc = 0.f;
  #pragma unroll
  for (int q = 0; q < 4; ++q) {
    const int m = (q * k2) & 3;  // state at n2=64q: angle = (pi/2)*q*k2
    float cc = (m == 0) ? 1.f : (m == 2) ? -1.f : 0.f;
    float ss = (m == 1) ? 1.f : (m == 3) ? -1.f : 0.f;
    float cp = cc + ss, cm = cc - ss;
    #pragma unroll 2
    for (int n2 = q * 64; n2 < q * 64 + 64; n2 += 4) {
      float c4[4], s4[4];
      *(float4*)c4 = *(const float4*)&C1[k1][n2];
      *(float4*)s4 = *(const float4*)&S1[k1][n2];
      #pragma unroll
      for (int jj = 0; jj < 4; ++jj) {
        acc = fmaf(c4[jj], cp, acc);
        acc = fmaf(s4[jj], cm, acc);
        float np = fmaf(rc2, cp, rs2 * cm);
        float nm = fmaf(rc2, cm, -rs2 * cp);
        cp = np; cm = nm;
      }
    }
  }
  xh[(size_t)half * 131072 + (size_t)img * 256 + t] = acc * INV_S;
}

// -------------------------------------------------------------------------
// K2: mode mix + inverse-DHT stage A, one block per (b,o).
//   res = 0.5 * sum_i [ x*(w+wn) + xn*(w-wn) ],  n-index = (-k) mod 16
//   W[n1][j]    = sum_k1 res[k1][j]*cos(THETA*k1*n1)   (rows 0..128)
//   W[n1][16+j] = sum_k1 res[k1][j]*sin(THETA*k1*n1)
// Stage B: all 256 threads: (row = t&127, h = t>>7) does j = 8h..8h+7.
// -------------------------------------------------------------------------
__global__ __launch_bounds__(256, 2) void k_mid(const float* __restrict__ xh,
                                                const float* __restrict__ w,
                                                float* __restrict__ Wout) {
  __shared__ float xs[CI][256];
  __shared__ __align__(16) float rsm[256];
  const int t = threadIdx.x;
  const int b = blockIdx.x >> 5;
  const int o = blockIdx.x & 31;

  #pragma unroll 8
  for (int i = 0; i < CI; ++i) {
    const size_t p = (size_t)(b * CI + i) * 256 + t;
    xs[i][t] = xh[p] + xh[131072 + p];  // sum the two k_fwd partials
  }
  __syncthreads();

  const int k1 = t >> 4, k2 = t & 15;
  const int tn = (((16 - k1) & 15) << 4) | ((16 - k2) & 15);
  float acc = 0.f;
  #pragma unroll 8
  for (int i = 0; i < CI; ++i) {
    const float* __restrict__ wrow = w + (size_t)(i * CO + o) * 256;
    float wp = wrow[t];
    float wn = wrow[tn];  // gather within 1 KB row: L1/L2 hit
    acc = fmaf(xs[i][t], wp + wn, acc);
    acc = fmaf(xs[i][tn], wp - wn, acc);
  }
  rsm[t] = 0.5f * acc;
  __syncthreads();

  const int row = t & 127, h = t >> 7;
  float cc[16], ss[16];
  #pragma unroll
  for (int k = 0; k < 16; ++k)
    sincosf(THETA * (float)((k * row) & 255), &ss[k], &cc[k]);
  float U[8], V[8];
  #pragma unroll
  for (int j = 0; j < 8; ++j) { U[j] = 0.f; V[j] = 0.f; }
  #pragma unroll
  for (int k = 0; k < 16; ++k) {
    float ra[8];
    *(float4*)&ra[0] = *(const float4*)&rsm[k * 16 + 8 * h];
    *(float4*)&ra[4] = *(const float4*)&rsm[k * 16 + 8 * h + 4];
    #pragma unroll
    for (int j = 0; j < 8; ++j) {
      U[j] = fmaf(cc[k], ra[j], U[j]);
      V[j] = fmaf(ss[k], ra[j], V[j]);
    }
  }
  float* __restrict__ wr = Wout + (size_t)blockIdx.x * 4160 + row * 32 + 8 * h;
  {
    float4 u0 = {U[0]*INV_S, U[1]*INV_S, U[2]*INV_S, U[3]*INV_S};
    float4 u1 = {U[4]*INV_S, U[5]*INV_S, U[6]*INV_S, U[7]*INV_S};
    float4 v0 = {V[0]*INV_S, V[1]*INV_S, V[2]*INV_S, V[3]*INV_S};
    float4 v1 = {V[4]*INV_S, V[5]*INV_S, V[6]*INV_S, V[7]*INV_S};
    *(float4*)&wr[0] = u0; *(float4*)&wr[4] = u1;
    *(float4*)&wr[16] = v0; *(float4*)&wr[20] = v1;
  }

  if (row == 0) {  // row 128: cos(pi*k1) = (-1)^k1, sin = 0
    float U8[8];
    #pragma unroll
    for (int j = 0; j < 8; ++j) U8[j] = 0.f;
    #pragma unroll
    for (int k = 0; k < 16; ++k) {
      float ra[8];
      *(float4*)&ra[0] = *(const float4*)&rsm[k * 16 + 8 * h];
      *(float4*)&ra[4] = *(const float4*)&rsm[k * 16 + 8 * h + 4];
      #pragma unroll
      for (int j = 0; j < 8; ++j)
        U8[j] = (k & 1) ? (U8[j] - ra[j]) : (U8[j] + ra[j]);
    }
    float* __restrict__ wr8 = Wout + (size_t)blockIdx.x * 4160 + 128 * 32 + 8 * h;
    float4 a0 = {U8[0]*INV_S, U8[1]*INV_S, U8[2]*INV_S, U8[3]*INV_S};
    float4 a1 = {U8[4]*INV_S, U8[5]*INV_S, U8[6]*INV_S, U8[7]*INV_S};
    float4 z = {0.f, 0.f, 0.f, 0.f};
    *(float4*)&wr8[0] = a0; *(float4*)&wr8[4] = a1;
    *(float4*)&wr8[16] = z; *(float4*)&wr8[20] = z;
  }
}

// -------------------------------------------------------------------------
// K3: inverse-DHT stage B. 2 blocks per (b,o); lane = column n2.
// W rows via uniform VMEM float4 loads (L2-hit); per-lane twiddles in
// registers; row-pair symmetry gives 2 output rows per W row. Zero LDS.
// launch_bounds(256,3): ~80 live VGPRs (cp/cm 32 + uu/vv 32 + misc) must
// NOT be capped to 64 -> that was a spill at (256,4).
// -------------------------------------------------------------------------
__global__ __launch_bounds__(256, 3) void k_invB(const float* __restrict__ Wb,
                                                 float* __restrict__ out) {
  const int t = threadIdx.x;
  const int img = blockIdx.x >> 1;
  const int half = blockIdx.x & 1;

  float cp[16], cm[16];
  #pragma unroll
  for (int k = 0; k < 16; ++k) {
    float s, c;
    sincosf(THETA * (float)((k * t) & 255), &s, &c);
    cp[k] = c + s;
    cm[k] = c - s;
  }

  const float* __restrict__ wbase = Wb + (size_t)img * 4160;
  float* __restrict__ op = out + (size_t)img * 65536 + t;

  const int n_lo = half ? 65 : 0;
  const int n_hi = half ? 128 : 64;
  #pragma unroll 2
  for (int n = n_lo; n <= n_hi; ++n) {
    float uu[16], vv[16];
    #pragma unroll
    for (int q = 0; q < 4; ++q) {
      *(float4*)&uu[4 * q] = *(const float4*)(wbase + n * 32 + 4 * q);
      *(float4*)&vv[4 * q] = *(const float4*)(wbase + n * 32 + 16 + 4 * q);
    }
    float a = 0.f, bsum = 0.f;
    #pragma unroll
    for (int k = 0; k < 16; ++k) {
      a = fmaf(uu[k], cp[k], a);
      bsum = fmaf(vv[k], cm[k], bsum);
    }
    op[(size_t)n * 256] = a + bsum;
    if (n >= 1 && n <= 127) op[(size_t)(256 - n) * 256] = a - bsum;
  }
}

extern "C" void kernel_launch(void* const* d_in, const int* in_sizes, int n_in,
                              void* d_out, int out_size, void* d_ws, size_t ws_size,
                              hipStream_t stream) {
  const float* x = (const float*)d_in[0];   // [16, 32, 256, 256] f32
  const float* w = (const float*)d_in[1];   // [32, 32, 16, 16]  f32
  float* out = (float*)d_out;               // [16, 32, 256, 256] f32

  float* xhb = (float*)d_ws;                // [2][512][256]  (1 MB, partials)
  float* Wb  = xhb + 262144;                // [512][130][32] (~8.5 MB)

  k_fwd<<<2 * 16 * CI, 256, 0, stream>>>(x, xhb);    // 1024 blocks
  k_mid<<<16 * CO, 256, 0, stream>>>(xhb, w, Wb);    // 512 blocks
  k_invB<<<2 * 16 * CO, 256, 0, stream>>>(Wb, out);  // 1024 blocks
}